// Round 3
// baseline (210.091 us; speedup 1.0000x reference)
//
#include <hip/hip_runtime.h>
#include <hip/hip_bf16.h>

// N=8192 rows, BD=64 code dim, CD=512 channel dim
#define NN 8192
#define BD 64
#define CDIM 512

typedef __attribute__((ext_vector_type(4))) float f32x4;
typedef __attribute__((ext_vector_type(4))) unsigned int u32x4;
typedef __attribute__((ext_vector_type(8))) __bf16 bf16x8;

// Fragment-major layouts (elems = unsigned short), frag = 512 ushorts = 1 KB:
//  adjF frag(it,kt): it=i/16 [0,512), kt=k/32 [0,256): off=(it*256+kt)*512+lane*8
//    lane=q*16+m holds adj[it*16+m][kt*32+q*8 .. +7]   (A-operand layout)
//  fcF  frag(nt,kt): nt=n/16 [0,32), kt=k/32 [0,256):  off=(nt*256+kt)*512+lane*8
//    lane holds fc2[kt*32+q*8 .. +7][nt*16+m]          (B-operand layout)
//  cbnF frag(it,ct): off=(it*16+ct)*512+lane*8  (A) ;  WF frag(nt,ct): off=(nt*16+ct)*512+lane*8 (B)

static __device__ __forceinline__ unsigned short f2bf(float x) {
    unsigned int u = __float_as_uint(x);
    u += 0x7fffu + ((u >> 16) & 1u);   // RTNE
    return (unsigned short)(u >> 16);
}

static __device__ __forceinline__ f32x4 mfma16(u32x4 a, u32x4 b, f32x4 c) {
    return __builtin_amdgcn_mfma_f32_16x16x32_bf16(
        __builtin_bit_cast(bf16x8, a), __builtin_bit_cast(bf16x8, b), c, 0, 0, 0);
}

static __device__ __forceinline__ u32x4 cvt8(const float* __restrict__ p) {
    float4 a = *(const float4*)p;
    float4 b = *(const float4*)(p + 4);
    u32x4 r;
    r.x = (unsigned)f2bf(a.x) | ((unsigned)f2bf(a.y) << 16);
    r.y = (unsigned)f2bf(a.z) | ((unsigned)f2bf(a.w) << 16);
    r.z = (unsigned)f2bf(b.x) | ((unsigned)f2bf(b.y) << 16);
    r.w = (unsigned)f2bf(b.z) | ((unsigned)f2bf(b.w) << 16);
    return r;
}

// async global->LDS DMA, 16B/lane. LDS dest = wave-uniform base + lane*16.
// Global src is per-lane (precomputed with +lane*8 ushorts).
static __device__ __forceinline__ void glds16(const unsigned short* g, const unsigned short* l) {
    __builtin_amdgcn_global_load_lds(
        (const __attribute__((address_space(1))) unsigned int*)(unsigned long long)g,
        (__attribute__((address_space(3))) unsigned int*)(unsigned int)(unsigned long long)l,
        16, 0, 0);
}

// adj = (max(1 - |2*dot - si - sj|/64, 0))^1.4
static __device__ __forceinline__ float adj_fn(float dot, float sij) {
    float x = fabsf(fmaf(2.0f, dot, -sij));
    float base = fmaxf(fmaf(-0.015625f, x, 1.0f), 0.0f);
    return exp2f(1.4f * __log2f(base));   // pow(0,1.4)=0 via -inf
}

// ---------------- prep: bbn -> bf16 (row-major), row sums s ----------------
__global__ void prep_kernel(const float* __restrict__ bbn,
                            unsigned short* __restrict__ tbf,
                            float* __restrict__ s) {
    int gid = blockIdx.x * blockDim.x + threadIdx.x;  // 16 threads/row
    int row = gid >> 4;
    int part = gid & 15;
    float4 v = *(const float4*)(bbn + row * BD + part * 4);
    ushort4 o;
    o.x = f2bf(v.x); o.y = f2bf(v.y); o.z = f2bf(v.z); o.w = f2bf(v.w);
    *(ushort4*)(tbf + row * BD + part * 4) = o;
    float ps = v.x + v.y + v.z + v.w;
    ps += __shfl_xor(ps, 1); ps += __shfl_xor(ps, 2);
    ps += __shfl_xor(ps, 4); ps += __shfl_xor(ps, 8);
    if (part == 0) s[row] = ps;
}

// ---------------- prep_cbn: cbn -> A-frag-major bf16 ----------------
__global__ __launch_bounds__(256) void prep_cbn_kernel(const float* __restrict__ cbn,
                                                       unsigned short* __restrict__ cbnF) {
    const int lane = threadIdx.x & 63;
    const int wave = threadIdx.x >> 6;
    const int m = lane & 15, q = lane >> 4;
#pragma unroll
    for (int t = 0; t < 4; ++t) {
        int f = blockIdx.x * 16 + wave * 4 + t;   // 8192 frags
        int it = f >> 4, ct = f & 15;
        u32x4 v = cvt8(cbn + (size_t)(it * 16 + m) * CDIM + ct * 32 + q * 8);
        *(u32x4*)(cbnF + (size_t)f * 512 + lane * 8) = v;
    }
}

// ---------------- prep_w: W -> B-frag-major bf16 ----------------
__global__ __launch_bounds__(256) void prep_w_kernel(const float* __restrict__ W,
                                                     unsigned short* __restrict__ WF) {
    const int lane = threadIdx.x & 63;
    const int wave = threadIdx.x >> 6;
    const int m = lane & 15, q = lane >> 4;
    int f = blockIdx.x * 4 + wave;   // 512 frags
    int nt = f >> 4, ct = f & 15;
    u32x4 v = cvt8(W + (size_t)(nt * 16 + m) * CDIM + ct * 32 + q * 8);
    *(u32x4*)(WF + (size_t)f * 512 + lane * 8) = v;
}

// ---------------- scoredeg: adjF = frag-major bf16 adj, d[i] = row sums ----------------
// grid (128 i-tiles, 16 j-chunks of 512) = 2048 blocks -> 8 blocks/CU.
// Double-buffered LDS: ONE barrier per 64-j tile (write p | barrier | read p || write p^1 ...).
__global__ __launch_bounds__(256) void scoredeg_kernel(const unsigned short* __restrict__ tbf,
                                                       const float* __restrict__ s,
                                                       float* __restrict__ d,
                                                       unsigned short* __restrict__ adjF) {
    const int lane = threadIdx.x & 63;
    const int wave = threadIdx.x >> 6;   // 0..3
    const int m = lane & 15, q = lane >> 4;
    const int i0 = blockIdx.x * 64;
    const int jbase = blockIdx.y * 512;

    __shared__ __align__(16) unsigned short Slds[2][64][72];  // 18.4 KB

    u32x4 afr[4][2];
    float si[4][4];
#pragma unroll
    for (int mt = 0; mt < 4; ++mt) {
#pragma unroll
        for (int ks = 0; ks < 2; ++ks)
            afr[mt][ks] = *(const u32x4*)(tbf + (i0 + mt * 16 + m) * BD + ks * 32 + q * 8);
#pragma unroll
        for (int r = 0; r < 4; ++r) si[mt][r] = s[i0 + mt * 16 + q * 4 + r];
    }
    float dsum[4][4] = {};

    // prefetch iter-0 B operand
    int jw = jbase + wave * 16;
    u32x4 b0 = *(const u32x4*)(tbf + (jw + m) * BD + q * 8);
    u32x4 b1 = *(const u32x4*)(tbf + (jw + m) * BD + 32 + q * 8);
    float sj = s[jw + m];

    for (int it8 = 0; it8 < 8; ++it8) {
        const int J = jbase + it8 * 64;
        const int p = it8 & 1;
        f32x4 c[4];
#pragma unroll
        for (int mt = 0; mt < 4; ++mt) {
            c[mt] = f32x4{0.f, 0.f, 0.f, 0.f};
            c[mt] = mfma16(afr[mt][0], b0, c[mt]);
            c[mt] = mfma16(afr[mt][1], b1, c[mt]);
        }
        // prefetch next iter's B while transform runs
        int jn = (it8 < 7) ? J + 64 + wave * 16 : jbase + wave * 16;
        u32x4 nb0 = *(const u32x4*)(tbf + (jn + m) * BD + q * 8);
        u32x4 nb1 = *(const u32x4*)(tbf + (jn + m) * BD + 32 + q * 8);
        float nsj = s[jn + m];
#pragma unroll
        for (int mt = 0; mt < 4; ++mt)
#pragma unroll
            for (int r = 0; r < 4; ++r) {
                float a = adj_fn(c[mt][r], si[mt][r] + sj);
                dsum[mt][r] += a;
                Slds[p][mt * 16 + q * 4 + r][wave * 16 + m] = f2bf(a);
            }
        __syncthreads();
        // frag store: wave w -> it-tile (i0/16 + w), k-tiles J/32 + {0,1}
#pragma unroll
        for (int ktl = 0; ktl < 2; ++ktl) {
            u32x4 v = *(const u32x4*)(&Slds[p][wave * 16 + m][ktl * 32 + q * 8]);
            *(u32x4*)(adjF + ((size_t)((i0 >> 4) + wave) * 256 + (J >> 5) + ktl) * 512 + lane * 8) = v;
        }
        b0 = nb0; b1 = nb1; sj = nsj;
    }

#pragma unroll
    for (int mt = 0; mt < 4; ++mt)
#pragma unroll
        for (int r = 0; r < 4; ++r) {
            float v = dsum[mt][r];
            v += __shfl_xor(v, 1); v += __shfl_xor(v, 2);
            v += __shfl_xor(v, 4); v += __shfl_xor(v, 8);
            if (m == 0) atomicAdd(&d[i0 + mt * 16 + q * 4 + r], v);
        }
}

// ---------------- dinv ----------------
__global__ void dinv_kernel(const float* __restrict__ d, float* __restrict__ dinv) {
    int i = blockIdx.x * 256 + threadIdx.x;
    dinv[i] = rsqrtf(d[i] + 1e-8f);
}

// ---------------- fc: fcF = frag-major bf16(dinv[i]*(cbnF @ WF + b)) ----------------
__global__ __launch_bounds__(256) void fc_kernel(const unsigned short* __restrict__ cbnF,
                                                 const unsigned short* __restrict__ WF,
                                                 const float* __restrict__ bias,
                                                 const float* __restrict__ dinv,
                                                 unsigned short* __restrict__ fcF) {
    const int lane = threadIdx.x & 63;
    const int wave = threadIdx.x >> 6;
    const int m = lane & 15, q = lane >> 4;
    const int i0 = blockIdx.x * 64;
    const int ntg = blockIdx.y * 4 + wave;   // 0..31

    const u32x4* Ag = (const u32x4*)cbnF;
    const u32x4* Bg = (const u32x4*)WF;

    f32x4 acc[4] = {};
#pragma unroll
    for (int ct = 0; ct < 16; ++ct) {
        u32x4 bfr = Bg[((size_t)ntg * 16 + ct) * 64 + lane];
#pragma unroll
        for (int mt = 0; mt < 4; ++mt) {
            u32x4 afr = Ag[(((size_t)(i0 >> 4) + mt) * 16 + ct) * 64 + lane];
            acc[mt] = mfma16(afr, bfr, acc[mt]);
        }
    }
    float bv = bias[ntg * 16 + m];
#pragma unroll
    for (int mt = 0; mt < 4; ++mt) {
        int i = i0 + mt * 16 + q * 4;   // conv2 k-index (fc row)
        ushort4 o;
        o.x = f2bf((acc[mt][0] + bv) * dinv[i + 0]);
        o.y = f2bf((acc[mt][1] + bv) * dinv[i + 1]);
        o.z = f2bf((acc[mt][2] + bv) * dinv[i + 2]);
        o.w = f2bf((acc[mt][3] + bv) * dinv[i + 3]);
        size_t off = ((size_t)ntg * 256 + (i >> 5)) * 512
                   + (size_t)((i >> 3) & 3) * 128 + m * 8 + (q & 1) * 4;
        *(ushort4*)(fcF + off) = o;
    }
}

// ---------------- conv2: out = sigmoid(dvi * (adj @ fc2)) — frag-major GEMM ----------------
// M=8192 N=512 K=8192. Block 128x128, 512 thr / 8 waves = (kg,rg,cg) 2x2x2;
// wave tile 64x64 (4x4 16^2 frags), kg halves split K, combined by LDS f32 reduce.
// BOTH operands staged via global_load_lds into a 128 KB dbuf (B dedup: L3 B traffic
// 1 GB -> 512 MB). ALL vmem issues at iter start => __syncthreads' vmcnt(0) drain is
// free (issue-to-drain = full 1240-cyc MFMA phase >= 900-cyc HBM latency). Round-1's
// 36% came from late B loads + bn->bq mid-phase waits exposing L3 latency each phase.
// Iter = K=128 (2 kt per kg): stage 64 KB (8 glds16/wave), 2 phases of 16 MFMA with
// pa/pb register dbuf (fine-grained lgkm waits by compiler), setprio around clusters.
// Swizzle: xcd=bid&7; the 4 cblk blocks of an iblk co-resident on ONE xcd => A slice
// fetched from HBM once, L2 serves re-reads.
__global__ __launch_bounds__(512, 2) void conv2_kernel(const unsigned short* __restrict__ adjF,
                                                       const unsigned short* __restrict__ fcF,
                                                       const float* __restrict__ dinv,
                                                       float* __restrict__ out) {
    const int bid = blockIdx.x;
    const int xcd = bid & 7;
    const int g = bid >> 3;               // 0..31
    const int iblk = (g >> 2) * 8 + xcd;  // 0..63
    const int cblk = g & 3;
    const int i0 = iblk * 128;

    const int lane = threadIdx.x & 63;
    const int wave = threadIdx.x >> 6;    // 0..7
    const int kg = wave >> 2;             // K half: kt [kg*128, kg*128+128)
    const int rg = (wave >> 1) & 1;       // row half (64 rows)
    const int cg = wave & 1;              // col half (64 cols)
    const int m = lane & 15, q = lane >> 4;

    // [buf][kg][ktl][slot][frag]: slot 0-7 = A it, 8-15 = B nt. 128 KB.
    __shared__ __align__(16) unsigned short S[2][2][2][16][512];

    // staging assignment: fid = wave*4+j in [0,32): kg2=fid>>4, ktl=(fid>>3)&1, sl=fid&7
    const unsigned short* sA[4];
    const unsigned short* sB[4];
    int kgj[4], ktlj[4], slj[4];
#pragma unroll
    for (int j = 0; j < 4; ++j) {
        int fid = wave * 4 + j;
        int kg2 = fid >> 4, ktl = (fid >> 3) & 1, sl = fid & 7;
        kgj[j] = kg2; ktlj[j] = ktl; slj[j] = sl;
        // kt(c) = kg2*128 + 2c + ktl  ->  +1024 ushorts per iter
        sA[j] = adjF + ((size_t)((i0 >> 4) + sl) * 256 + kg2 * 128 + ktl) * 512 + lane * 8;
        sB[j] = fcF  + ((size_t)(cblk * 8 + sl) * 256 + kg2 * 128 + ktl) * 512 + lane * 8;
    }

    u32x4 paC[4], pbC[4], paN[4], pbN[4];
    f32x4 acc[4][4] = {};

    // prologue: stage iter 0 into buf 0, then preload phase-0 frags
#pragma unroll
    for (int j = 0; j < 4; ++j) {
        glds16(sA[j], &S[0][kgj[j]][ktlj[j]][slj[j]][0]);
        glds16(sB[j], &S[0][kgj[j]][ktlj[j]][8 + slj[j]][0]);
    }
    __syncthreads();
#pragma unroll
    for (int t = 0; t < 4; ++t) {
        paC[t] = *(const u32x4*)&S[0][kg][0][rg * 4 + t][lane * 8];
        pbC[t] = *(const u32x4*)&S[0][kg][0][8 + cg * 4 + t][lane * 8];
    }

    for (int c = 0; c < 64; ++c) {
        const int cur = c & 1, nxt = cur ^ 1;
        // all vmem for iter c+1 issued NOW (drained ~1240 cyc later at the barrier)
        if (c < 63) {
            const size_t co = (size_t)(c + 1) * 1024;
#pragma unroll
            for (int j = 0; j < 4; ++j) {
                glds16(sA[j] + co, &S[nxt][kgj[j]][ktlj[j]][slj[j]][0]);
                glds16(sB[j] + co, &S[nxt][kgj[j]][ktlj[j]][8 + slj[j]][0]);
            }
        }
        __builtin_amdgcn_sched_barrier(0);   // pin DMA issue before compute
        // phase 0: issue phase-1 ds_reads, compute phase-0
#pragma unroll
        for (int t = 0; t < 4; ++t) {
            paN[t] = *(const u32x4*)&S[cur][kg][1][rg * 4 + t][lane * 8];
            pbN[t] = *(const u32x4*)&S[cur][kg][1][8 + cg * 4 + t][lane * 8];
        }
        __builtin_amdgcn_s_setprio(1);
#pragma unroll
        for (int mt = 0; mt < 4; ++mt)
#pragma unroll
            for (int ct = 0; ct < 4; ++ct)
                acc[mt][ct] = mfma16(paC[mt], pbC[ct], acc[mt][ct]);
        __builtin_amdgcn_s_setprio(0);
        // phase 1
        __builtin_amdgcn_s_setprio(1);
#pragma unroll
        for (int mt = 0; mt < 4; ++mt)
#pragma unroll
            for (int ct = 0; ct < 4; ++ct)
                acc[mt][ct] = mfma16(paN[mt], pbN[ct], acc[mt][ct]);
        __builtin_amdgcn_s_setprio(0);
        __syncthreads();                     // vmcnt(0): DMAs issued 1 iter ago -> free
        if (c < 63) {
#pragma unroll
            for (int t = 0; t < 4; ++t) {
                paC[t] = *(const u32x4*)&S[nxt][kg][0][rg * 4 + t][lane * 8];
                pbC[t] = *(const u32x4*)&S[nxt][kg][0][8 + cg * 4 + t][lane * 8];
            }
        }
    }

    // cross-kg combine: kg1 publishes acc (f32, stride 132 to dodge bank conflicts),
    // kg0 adds + epilogue. Reuses S (all reads fenced by final loop barrier).
    float* red = (float*)&S[0][0][0][0][0];   // 128*132*4 = 67.6 KB < 128 KB
    if (kg == 1) {
#pragma unroll
        for (int mt = 0; mt < 4; ++mt)
#pragma unroll
            for (int ct = 0; ct < 4; ++ct)
#pragma unroll
                for (int r = 0; r < 4; ++r)
                    red[(rg * 64 + mt * 16 + q * 4 + r) * 132 + cg * 64 + ct * 16 + m] = acc[mt][ct][r];
    }
    __syncthreads();
    if (kg == 0) {
#pragma unroll
        for (int mt = 0; mt < 4; ++mt)
#pragma unroll
            for (int ct = 0; ct < 4; ++ct)
#pragma unroll
                for (int r = 0; r < 4; ++r) {
                    int lrow = rg * 64 + mt * 16 + q * 4 + r;
                    int row = i0 + lrow;
                    int lcol = cg * 64 + ct * 16 + m;
                    float v = acc[mt][ct][r] + red[lrow * 132 + lcol];
                    float xv = v * dinv[row];
                    out[(size_t)row * CDIM + cblk * 128 + lcol] = 1.0f / (1.0f + __expf(-xv));
                }
    }
}

extern "C" void kernel_launch(void* const* d_in, const int* in_sizes, int n_in,
                              void* d_out, int out_size, void* d_ws, size_t ws_size,
                              hipStream_t stream) {
    const float* bbn = (const float*)d_in[0];
    const float* cbn = (const float*)d_in[1];
    const float* W   = (const float*)d_in[2];
    const float* b   = (const float*)d_in[3];
    float* out = (float*)d_out;  // reference output is float32

    char* ws = (char*)d_ws;
    unsigned short* tbf  = (unsigned short*)(ws);                 // 1 MB
    float* s             = (float*)(ws + (1u << 20));             // 32 KB
    float* d             = (float*)(ws + (1u << 20) + 32768);     // 32 KB
    float* dinv          = (float*)(ws + (1u << 20) + 65536);     // 32 KB
    unsigned short* fcF  = (unsigned short*)(ws + (2u << 20));    // 8 MB
    unsigned short* cbnF = (unsigned short*)(ws + (10u << 20));   // 8 MB
    unsigned short* WF   = (unsigned short*)(ws + (18u << 20));   // 0.5 MB
    unsigned short* adjF = (unsigned short*)(ws + (19u << 20));   // 128 MiB

    prep_kernel<<<NN * 16 / 256, 256, 0, stream>>>(bbn, tbf, s);
    prep_cbn_kernel<<<512, 256, 0, stream>>>(cbn, cbnF);
    prep_w_kernel<<<128, 256, 0, stream>>>(W, WF);
    hipMemsetAsync(d, 0, NN * sizeof(float), stream);
    scoredeg_kernel<<<dim3(NN / 64, 16), 256, 0, stream>>>(tbf, s, d, adjF);
    dinv_kernel<<<NN / 256, 256, 0, stream>>>(d, dinv);
    fc_kernel<<<dim3(NN / 64, 8), 256, 0, stream>>>(cbnF, WF, b, dinv, fcF);
    conv2_kernel<<<256, 512, 0, stream>>>(adjF, fcF, dinv, out);
}

// Round 4
// 206.343 us; speedup vs baseline: 1.0182x; 1.0182x over previous
//
#include <hip/hip_runtime.h>
#include <hip/hip_bf16.h>

// N=8192 rows, BD=64 code dim, CD=512 channel dim
#define NN 8192
#define BD 64
#define CDIM 512

typedef __attribute__((ext_vector_type(4))) float f32x4;
typedef __attribute__((ext_vector_type(4))) unsigned int u32x4;
typedef __attribute__((ext_vector_type(8))) __bf16 bf16x8;

// Fragment-major layouts (elems = unsigned short), frag = 512 ushorts = 1 KB:
//  adjF frag(it,kt): it=i/16 [0,512), kt=k/32 [0,256): off=(it*256+kt)*512+lane*8
//    lane=q*16+m holds adj[it*16+m][kt*32+q*8 .. +7]   (A-operand layout)
//  fcF  frag(nt,kt): nt=n/16 [0,32), kt=k/32 [0,256):  off=(nt*256+kt)*512+lane*8
//    lane holds fc2[kt*32+q*8 .. +7][nt*16+m]          (B-operand layout)
//  cbnF frag(it,ct): off=(it*16+ct)*512+lane*8  (A) ;  WF frag(nt,ct): off=(nt*16+ct)*512+lane*8 (B)

static __device__ __forceinline__ unsigned short f2bf(float x) {
    unsigned int u = __float_as_uint(x);
    u += 0x7fffu + ((u >> 16) & 1u);   // RTNE
    return (unsigned short)(u >> 16);
}

static __device__ __forceinline__ f32x4 mfma16(u32x4 a, u32x4 b, f32x4 c) {
    return __builtin_amdgcn_mfma_f32_16x16x32_bf16(
        __builtin_bit_cast(bf16x8, a), __builtin_bit_cast(bf16x8, b), c, 0, 0, 0);
}

static __device__ __forceinline__ u32x4 cvt8(const float* __restrict__ p) {
    float4 a = *(const float4*)p;
    float4 b = *(const float4*)(p + 4);
    u32x4 r;
    r.x = (unsigned)f2bf(a.x) | ((unsigned)f2bf(a.y) << 16);
    r.y = (unsigned)f2bf(a.z) | ((unsigned)f2bf(a.w) << 16);
    r.z = (unsigned)f2bf(b.x) | ((unsigned)f2bf(b.y) << 16);
    r.w = (unsigned)f2bf(b.z) | ((unsigned)f2bf(b.w) << 16);
    return r;
}

// async global->LDS DMA, 16B/lane. LDS dest = wave-uniform base + lane*16.
// Global src is per-lane (precomputed with +lane*8 ushorts).
static __device__ __forceinline__ void glds16(const unsigned short* g, const unsigned short* l) {
    __builtin_amdgcn_global_load_lds(
        (const __attribute__((address_space(1))) unsigned int*)(unsigned long long)g,
        (__attribute__((address_space(3))) unsigned int*)(unsigned int)(unsigned long long)l,
        16, 0, 0);
}

// adj = (max(1 - |2*dot - si - sj|/64, 0))^1.4
static __device__ __forceinline__ float adj_fn(float dot, float sij) {
    float x = fabsf(fmaf(2.0f, dot, -sij));
    float base = fmaxf(fmaf(-0.015625f, x, 1.0f), 0.0f);
    return exp2f(1.4f * __log2f(base));   // pow(0,1.4)=0 via -inf
}

// ---------------- prep: bbn -> bf16 (row-major), row sums s ----------------
__global__ void prep_kernel(const float* __restrict__ bbn,
                            unsigned short* __restrict__ tbf,
                            float* __restrict__ s) {
    int gid = blockIdx.x * blockDim.x + threadIdx.x;  // 16 threads/row
    int row = gid >> 4;
    int part = gid & 15;
    float4 v = *(const float4*)(bbn + row * BD + part * 4);
    ushort4 o;
    o.x = f2bf(v.x); o.y = f2bf(v.y); o.z = f2bf(v.z); o.w = f2bf(v.w);
    *(ushort4*)(tbf + row * BD + part * 4) = o;
    float ps = v.x + v.y + v.z + v.w;
    ps += __shfl_xor(ps, 1); ps += __shfl_xor(ps, 2);
    ps += __shfl_xor(ps, 4); ps += __shfl_xor(ps, 8);
    if (part == 0) s[row] = ps;
}

// ---------------- prep_cbn: cbn -> A-frag-major bf16 ----------------
__global__ __launch_bounds__(256) void prep_cbn_kernel(const float* __restrict__ cbn,
                                                       unsigned short* __restrict__ cbnF) {
    const int lane = threadIdx.x & 63;
    const int wave = threadIdx.x >> 6;
    const int m = lane & 15, q = lane >> 4;
#pragma unroll
    for (int t = 0; t < 4; ++t) {
        int f = blockIdx.x * 16 + wave * 4 + t;   // 8192 frags
        int it = f >> 4, ct = f & 15;
        u32x4 v = cvt8(cbn + (size_t)(it * 16 + m) * CDIM + ct * 32 + q * 8);
        *(u32x4*)(cbnF + (size_t)f * 512 + lane * 8) = v;
    }
}

// ---------------- prep_w: W -> B-frag-major bf16 ----------------
__global__ __launch_bounds__(256) void prep_w_kernel(const float* __restrict__ W,
                                                     unsigned short* __restrict__ WF) {
    const int lane = threadIdx.x & 63;
    const int wave = threadIdx.x >> 6;
    const int m = lane & 15, q = lane >> 4;
    int f = blockIdx.x * 4 + wave;   // 512 frags
    int nt = f >> 4, ct = f & 15;
    u32x4 v = cvt8(W + (size_t)(nt * 16 + m) * CDIM + ct * 32 + q * 8);
    *(u32x4*)(WF + (size_t)f * 512 + lane * 8) = v;
}

// ---------------- scoredeg: adjF = frag-major bf16 adj, d[i] = row sums ----------------
// grid (128 i-tiles, 16 j-chunks of 512) = 2048 blocks -> 8 blocks/CU.
// Double-buffered LDS: ONE barrier per 64-j tile (write p | barrier | read p || write p^1 ...).
__global__ __launch_bounds__(256) void scoredeg_kernel(const unsigned short* __restrict__ tbf,
                                                       const float* __restrict__ s,
                                                       float* __restrict__ d,
                                                       unsigned short* __restrict__ adjF) {
    const int lane = threadIdx.x & 63;
    const int wave = threadIdx.x >> 6;   // 0..3
    const int m = lane & 15, q = lane >> 4;
    const int i0 = blockIdx.x * 64;
    const int jbase = blockIdx.y * 512;

    __shared__ __align__(16) unsigned short Slds[2][64][72];  // 18.4 KB

    u32x4 afr[4][2];
    float si[4][4];
#pragma unroll
    for (int mt = 0; mt < 4; ++mt) {
#pragma unroll
        for (int ks = 0; ks < 2; ++ks)
            afr[mt][ks] = *(const u32x4*)(tbf + (i0 + mt * 16 + m) * BD + ks * 32 + q * 8);
#pragma unroll
        for (int r = 0; r < 4; ++r) si[mt][r] = s[i0 + mt * 16 + q * 4 + r];
    }
    float dsum[4][4] = {};

    // prefetch iter-0 B operand
    int jw = jbase + wave * 16;
    u32x4 b0 = *(const u32x4*)(tbf + (jw + m) * BD + q * 8);
    u32x4 b1 = *(const u32x4*)(tbf + (jw + m) * BD + 32 + q * 8);
    float sj = s[jw + m];

    for (int it8 = 0; it8 < 8; ++it8) {
        const int J = jbase + it8 * 64;
        const int p = it8 & 1;
        f32x4 c[4];
#pragma unroll
        for (int mt = 0; mt < 4; ++mt) {
            c[mt] = f32x4{0.f, 0.f, 0.f, 0.f};
            c[mt] = mfma16(afr[mt][0], b0, c[mt]);
            c[mt] = mfma16(afr[mt][1], b1, c[mt]);
        }
        // prefetch next iter's B while transform runs
        int jn = (it8 < 7) ? J + 64 + wave * 16 : jbase + wave * 16;
        u32x4 nb0 = *(const u32x4*)(tbf + (jn + m) * BD + q * 8);
        u32x4 nb1 = *(const u32x4*)(tbf + (jn + m) * BD + 32 + q * 8);
        float nsj = s[jn + m];
#pragma unroll
        for (int mt = 0; mt < 4; ++mt)
#pragma unroll
            for (int r = 0; r < 4; ++r) {
                float a = adj_fn(c[mt][r], si[mt][r] + sj);
                dsum[mt][r] += a;
                Slds[p][mt * 16 + q * 4 + r][wave * 16 + m] = f2bf(a);
            }
        __syncthreads();
        // frag store: wave w -> it-tile (i0/16 + w), k-tiles J/32 + {0,1}
#pragma unroll
        for (int ktl = 0; ktl < 2; ++ktl) {
            u32x4 v = *(const u32x4*)(&Slds[p][wave * 16 + m][ktl * 32 + q * 8]);
            *(u32x4*)(adjF + ((size_t)((i0 >> 4) + wave) * 256 + (J >> 5) + ktl) * 512 + lane * 8) = v;
        }
        b0 = nb0; b1 = nb1; sj = nsj;
    }

#pragma unroll
    for (int mt = 0; mt < 4; ++mt)
#pragma unroll
        for (int r = 0; r < 4; ++r) {
            float v = dsum[mt][r];
            v += __shfl_xor(v, 1); v += __shfl_xor(v, 2);
            v += __shfl_xor(v, 4); v += __shfl_xor(v, 8);
            if (m == 0) atomicAdd(&d[i0 + mt * 16 + q * 4 + r], v);
        }
}

// ---------------- dinv ----------------
__global__ void dinv_kernel(const float* __restrict__ d, float* __restrict__ dinv) {
    int i = blockIdx.x * 256 + threadIdx.x;
    dinv[i] = rsqrtf(d[i] + 1e-8f);
}

// ---------------- fc: fcF = frag-major bf16(dinv[i]*(cbnF @ WF + b)) ----------------
__global__ __launch_bounds__(256) void fc_kernel(const unsigned short* __restrict__ cbnF,
                                                 const unsigned short* __restrict__ WF,
                                                 const float* __restrict__ bias,
                                                 const float* __restrict__ dinv,
                                                 unsigned short* __restrict__ fcF) {
    const int lane = threadIdx.x & 63;
    const int wave = threadIdx.x >> 6;
    const int m = lane & 15, q = lane >> 4;
    const int i0 = blockIdx.x * 64;
    const int ntg = blockIdx.y * 4 + wave;   // 0..31

    const u32x4* Ag = (const u32x4*)cbnF;
    const u32x4* Bg = (const u32x4*)WF;

    f32x4 acc[4] = {};
#pragma unroll
    for (int ct = 0; ct < 16; ++ct) {
        u32x4 bfr = Bg[((size_t)ntg * 16 + ct) * 64 + lane];
#pragma unroll
        for (int mt = 0; mt < 4; ++mt) {
            u32x4 afr = Ag[(((size_t)(i0 >> 4) + mt) * 16 + ct) * 64 + lane];
            acc[mt] = mfma16(afr, bfr, acc[mt]);
        }
    }
    float bv = bias[ntg * 16 + m];
#pragma unroll
    for (int mt = 0; mt < 4; ++mt) {
        int i = i0 + mt * 16 + q * 4;   // conv2 k-index (fc row)
        ushort4 o;
        o.x = f2bf((acc[mt][0] + bv) * dinv[i + 0]);
        o.y = f2bf((acc[mt][1] + bv) * dinv[i + 1]);
        o.z = f2bf((acc[mt][2] + bv) * dinv[i + 2]);
        o.w = f2bf((acc[mt][3] + bv) * dinv[i + 3]);
        size_t off = ((size_t)ntg * 256 + (i >> 5)) * 512
                   + (size_t)((i >> 3) & 3) * 128 + m * 8 + (q & 1) * 4;
        *(ushort4*)(fcF + off) = o;
    }
}

// ---------------- conv2: out = sigmoid(dvi * (adj @ fc2)) — frag-major GEMM ----------------
// M=8192 N=512 K=8192. Block 128x128, 512 thr / 8 waves = (kg,rg,cg) 2x2x2;
// wave tile 64x64 (4x4 16^2 frags), kg halves take alternating kt, LDS f32 reduce at end.
// COUNTED-VMCNT RING (T3+T4): chunk = K=64 (32 frags, 32 KB), 4-slot LDS ring (128 KB),
// 3 chunks in flight (12 glds16/wave outstanding). Per iter: sched_barrier ->
// s_waitcnt vmcnt(8) (oldest chunk done, 8 STILL FLYING - never drains to 0) ->
// raw s_barrier -> issue chunk h+3 -> 8 ds_read_b128 -> 16 MFMA under setprio(1).
// This kills the m97-ceiling drain: __syncthreads' implicit vmcnt(0) exposed DMA
// latency every iter and pinned 3 different schedules at 36-37% MfmaUtil.
// Race safety: issue is post-barrier and targets S[(h+3)&3] = chunk h-1's slot, whose
// reads finished before any wave reached barrier(h); chunk-h reads are safe because
// each wave waited its own chunk-h DMAs pre-barrier. No other vmem in loop.
// Swizzle: xcd=bid&7; 4 cblk blocks of an iblk co-resident on ONE xcd => A slice
// fetched from HBM once, L2 serves re-reads.
__global__ __launch_bounds__(512, 2) void conv2_kernel(const unsigned short* __restrict__ adjF,
                                                       const unsigned short* __restrict__ fcF,
                                                       const float* __restrict__ dinv,
                                                       float* __restrict__ out) {
    const int bid = blockIdx.x;
    const int xcd = bid & 7;
    const int g = bid >> 3;               // 0..31
    const int iblk = (g >> 2) * 8 + xcd;  // 0..63
    const int cblk = g & 3;
    const int i0 = iblk * 128;

    const int lane = threadIdx.x & 63;
    const int wave = threadIdx.x >> 6;    // 0..7
    const int kg = wave >> 2;             // kt parity: kg0 -> even kt, kg1 -> odd kt
    const int rg = (wave >> 1) & 1;       // row half (64 rows)
    const int cg = wave & 1;              // col half (64 cols)
    const int m = lane & 15, q = lane >> 4;

    // 4-slot ring of K=64 chunks: [ring][slot][frag]; slot 0-15 = A(ktl*8+it),
    // 16-31 = B(ktl*8+nt). 128 KB.
    __shared__ __align__(16) unsigned short S[4][32][512];

    // staging: fid = wave*4+j in [0,32): isB=fid>>4, ktl=(fid>>3)&1, sl=fid&7
    const unsigned short* src[4];
    int slot[4];
#pragma unroll
    for (int j = 0; j < 4; ++j) {
        int fid = wave * 4 + j;
        int isB = fid >> 4;
        int ktl = (fid >> 3) & 1;
        int sl = fid & 7;
        slot[j] = isB * 16 + ktl * 8 + sl;
        src[j] = isB
            ? fcF  + ((size_t)(cblk * 8 + sl) * 256 + ktl) * 512 + lane * 8
            : adjF + ((size_t)((i0 >> 4) + sl) * 256 + ktl) * 512 + lane * 8;
        // chunk h covers kt = 2h+ktl -> advance 1024 ushorts (2 KB) per chunk
    }

    f32x4 acc[4][4] = {};

    // prologue: issue chunks 0..2 (12 outstanding glds16 per wave)
#pragma unroll
    for (int h = 0; h < 3; ++h)
#pragma unroll
        for (int j = 0; j < 4; ++j)
            glds16(src[j] + (size_t)h * 1024, &S[h][slot[j]][0]);

    const int arow = kg * 8 + rg * 4;        // this wave's A slot base
    const int brow = 16 + kg * 8 + cg * 4;   // this wave's B slot base

#define CONV2_STEP(HH, WAITN)                                                   \
    {                                                                           \
        __builtin_amdgcn_sched_barrier(0);                                      \
        asm volatile("s_waitcnt vmcnt(" #WAITN ")" ::: "memory");               \
        __builtin_amdgcn_s_barrier();                                           \
        __builtin_amdgcn_sched_barrier(0);                                      \
        if ((HH) < 125) {                                                       \
            const int hn_ = (HH) + 3;                                           \
            _Pragma("unroll")                                                   \
            for (int j = 0; j < 4; ++j)                                         \
                glds16(src[j] + (size_t)hn_ * 1024, &S[hn_ & 3][slot[j]][0]);   \
        }                                                                       \
        __builtin_amdgcn_sched_barrier(0);                                      \
        u32x4 pa_[4], pb_[4];                                                   \
        _Pragma("unroll")                                                       \
        for (int t = 0; t < 4; ++t) {                                           \
            pa_[t] = *(const u32x4*)&S[(HH) & 3][arow + t][lane * 8];           \
            pb_[t] = *(const u32x4*)&S[(HH) & 3][brow + t][lane * 8];           \
        }                                                                       \
        __builtin_amdgcn_s_setprio(1);                                          \
        _Pragma("unroll")                                                       \
        for (int mt = 0; mt < 4; ++mt)                                          \
            _Pragma("unroll")                                                   \
            for (int ct = 0; ct < 4; ++ct)                                      \
                acc[mt][ct] = mfma16(pa_[mt], pb_[ct], acc[mt][ct]);            \
        __builtin_amdgcn_s_setprio(0);                                          \
    }

    for (int h = 0; h < 126; ++h) CONV2_STEP(h, 8);
    CONV2_STEP(126, 4);
    CONV2_STEP(127, 0);
#undef CONV2_STEP

    // cross-kg combine: kg1 publishes acc (f32, stride 132 to dodge bank conflicts),
    // kg0 adds + epilogue. Reuses S: red spans 67.6 KB (ring slots 0-2); the only
    // post-loop LDS reads are of ring slot 3 (96-128 KB) during iter 127 - disjoint,
    // and all waves passed barrier(127) before any wave enters the epilogue.
    float* red = (float*)&S[0][0][0];   // 128*132*4 = 67.6 KB < 128 KB
    if (kg == 1) {
#pragma unroll
        for (int mt = 0; mt < 4; ++mt)
#pragma unroll
            for (int ct = 0; ct < 4; ++ct)
#pragma unroll
                for (int r = 0; r < 4; ++r)
                    red[(rg * 64 + mt * 16 + q * 4 + r) * 132 + cg * 64 + ct * 16 + m] = acc[mt][ct][r];
    }
    __syncthreads();
    if (kg == 0) {
#pragma unroll
        for (int mt = 0; mt < 4; ++mt)
#pragma unroll
            for (int ct = 0; ct < 4; ++ct)
#pragma unroll
                for (int r = 0; r < 4; ++r) {
                    int lrow = rg * 64 + mt * 16 + q * 4 + r;
                    int row = i0 + lrow;
                    int lcol = cg * 64 + ct * 16 + m;
                    float v = acc[mt][ct][r] + red[lrow * 132 + lcol];
                    float xv = v * dinv[row];
                    out[(size_t)row * CDIM + cblk * 128 + lcol] = 1.0f / (1.0f + __expf(-xv));
                }
    }
}

extern "C" void kernel_launch(void* const* d_in, const int* in_sizes, int n_in,
                              void* d_out, int out_size, void* d_ws, size_t ws_size,
                              hipStream_t stream) {
    const float* bbn = (const float*)d_in[0];
    const float* cbn = (const float*)d_in[1];
    const float* W   = (const float*)d_in[2];
    const float* b   = (const float*)d_in[3];
    float* out = (float*)d_out;  // reference output is float32

    char* ws = (char*)d_ws;
    unsigned short* tbf  = (unsigned short*)(ws);                 // 1 MB
    float* s             = (float*)(ws + (1u << 20));             // 32 KB
    float* d             = (float*)(ws + (1u << 20) + 32768);     // 32 KB
    float* dinv          = (float*)(ws + (1u << 20) + 65536);     // 32 KB
    unsigned short* fcF  = (unsigned short*)(ws + (2u << 20));    // 8 MB
    unsigned short* cbnF = (unsigned short*)(ws + (10u << 20));   // 8 MB
    unsigned short* WF   = (unsigned short*)(ws + (18u << 20));   // 0.5 MB
    unsigned short* adjF = (unsigned short*)(ws + (19u << 20));   // 128 MiB

    prep_kernel<<<NN * 16 / 256, 256, 0, stream>>>(bbn, tbf, s);
    prep_cbn_kernel<<<512, 256, 0, stream>>>(cbn, cbnF);
    prep_w_kernel<<<128, 256, 0, stream>>>(W, WF);
    hipMemsetAsync(d, 0, NN * sizeof(float), stream);
    scoredeg_kernel<<<dim3(NN / 64, 16), 256, 0, stream>>>(tbf, s, d, adjF);
    dinv_kernel<<<NN / 256, 256, 0, stream>>>(d, dinv);
    fc_kernel<<<dim3(NN / 64, 8), 256, 0, stream>>>(cbnF, WF, b, dinv, fcF);
    conv2_kernel<<<256, 512, 0, stream>>>(adjF, fcF, dinv, out);
}

// Round 5
// 206.242 us; speedup vs baseline: 1.0187x; 1.0005x over previous
//
#include <hip/hip_runtime.h>
#include <hip/hip_bf16.h>

// N=8192 rows, BD=64 code dim, CD=512 channel dim
#define NN 8192
#define BD 64
#define CDIM 512

typedef __attribute__((ext_vector_type(4))) float f32x4;
typedef __attribute__((ext_vector_type(4))) unsigned int u32x4;
typedef __attribute__((ext_vector_type(8))) __bf16 bf16x8;

// Fragment-major layouts (elems = unsigned short), frag = 512 ushorts = 1 KB:
//  adjF frag(it,kt): it=i/16 [0,512), kt=k/32 [0,256): off=(it*256+kt)*512+lane*8
//    lane=q*16+m holds adj[it*16+m][kt*32+q*8 .. +7]   (A-operand layout)
//  fcF  frag(nt,kt): nt=n/16 [0,32), kt=k/32 [0,256):  off=(nt*256+kt)*512+lane*8
//    lane holds fc2[kt*32+q*8 .. +7][nt*16+m]          (B-operand layout)
//  cbnF frag(it,ct): off=(it*16+ct)*512+lane*8  (A) ;  WF frag(nt,ct): off=(nt*16+ct)*512+lane*8 (B)

static __device__ __forceinline__ unsigned short f2bf(float x) {
    unsigned int u = __float_as_uint(x);
    u += 0x7fffu + ((u >> 16) & 1u);   // RTNE
    return (unsigned short)(u >> 16);
}

static __device__ __forceinline__ f32x4 mfma16(u32x4 a, u32x4 b, f32x4 c) {
    return __builtin_amdgcn_mfma_f32_16x16x32_bf16(
        __builtin_bit_cast(bf16x8, a), __builtin_bit_cast(bf16x8, b), c, 0, 0, 0);
}

static __device__ __forceinline__ u32x4 cvt8(const float* __restrict__ p) {
    float4 a = *(const float4*)p;
    float4 b = *(const float4*)(p + 4);
    u32x4 r;
    r.x = (unsigned)f2bf(a.x) | ((unsigned)f2bf(a.y) << 16);
    r.y = (unsigned)f2bf(a.z) | ((unsigned)f2bf(a.w) << 16);
    r.z = (unsigned)f2bf(b.x) | ((unsigned)f2bf(b.y) << 16);
    r.w = (unsigned)f2bf(b.z) | ((unsigned)f2bf(b.w) << 16);
    return r;
}

// async global->LDS DMA, 16B/lane. LDS dest = wave-uniform base + lane*16.
// Global src is per-lane (precomputed with +lane*8 ushorts).
static __device__ __forceinline__ void glds16(const unsigned short* g, const unsigned short* l) {
    __builtin_amdgcn_global_load_lds(
        (const __attribute__((address_space(1))) unsigned int*)(unsigned long long)g,
        (__attribute__((address_space(3))) unsigned int*)(unsigned int)(unsigned long long)l,
        16, 0, 0);
}

// adj = (max(1 - |2*dot - si - sj|/64, 0))^1.4
static __device__ __forceinline__ float adj_fn(float dot, float sij) {
    float x = fabsf(fmaf(2.0f, dot, -sij));
    float base = fmaxf(fmaf(-0.015625f, x, 1.0f), 0.0f);
    return exp2f(1.4f * __log2f(base));   // pow(0,1.4)=0 via -inf
}

// ---------------- prep: bbn -> bf16 (row-major), row sums s ----------------
__global__ void prep_kernel(const float* __restrict__ bbn,
                            unsigned short* __restrict__ tbf,
                            float* __restrict__ s) {
    int gid = blockIdx.x * blockDim.x + threadIdx.x;  // 16 threads/row
    int row = gid >> 4;
    int part = gid & 15;
    float4 v = *(const float4*)(bbn + row * BD + part * 4);
    ushort4 o;
    o.x = f2bf(v.x); o.y = f2bf(v.y); o.z = f2bf(v.z); o.w = f2bf(v.w);
    *(ushort4*)(tbf + row * BD + part * 4) = o;
    float ps = v.x + v.y + v.z + v.w;
    ps += __shfl_xor(ps, 1); ps += __shfl_xor(ps, 2);
    ps += __shfl_xor(ps, 4); ps += __shfl_xor(ps, 8);
    if (part == 0) s[row] = ps;
}

// ---------------- prep_cbn: cbn -> A-frag-major bf16 ----------------
__global__ __launch_bounds__(256) void prep_cbn_kernel(const float* __restrict__ cbn,
                                                       unsigned short* __restrict__ cbnF) {
    const int lane = threadIdx.x & 63;
    const int wave = threadIdx.x >> 6;
    const int m = lane & 15, q = lane >> 4;
#pragma unroll
    for (int t = 0; t < 4; ++t) {
        int f = blockIdx.x * 16 + wave * 4 + t;   // 8192 frags
        int it = f >> 4, ct = f & 15;
        u32x4 v = cvt8(cbn + (size_t)(it * 16 + m) * CDIM + ct * 32 + q * 8);
        *(u32x4*)(cbnF + (size_t)f * 512 + lane * 8) = v;
    }
}

// ---------------- prep_w: W -> B-frag-major bf16 ----------------
__global__ __launch_bounds__(256) void prep_w_kernel(const float* __restrict__ W,
                                                     unsigned short* __restrict__ WF) {
    const int lane = threadIdx.x & 63;
    const int wave = threadIdx.x >> 6;
    const int m = lane & 15, q = lane >> 4;
    int f = blockIdx.x * 4 + wave;   // 512 frags
    int nt = f >> 4, ct = f & 15;
    u32x4 v = cvt8(W + (size_t)(nt * 16 + m) * CDIM + ct * 32 + q * 8);
    *(u32x4*)(WF + (size_t)f * 512 + lane * 8) = v;
}

// ---------------- scoredeg: adjF = frag-major bf16 adj, d[i] = row sums ----------------
// grid (128 i-tiles, 16 j-chunks of 512) = 2048 blocks -> 8 blocks/CU.
// Double-buffered LDS: ONE barrier per 64-j tile (write p | barrier | read p || write p^1 ...).
__global__ __launch_bounds__(256) void scoredeg_kernel(const unsigned short* __restrict__ tbf,
                                                       const float* __restrict__ s,
                                                       float* __restrict__ d,
                                                       unsigned short* __restrict__ adjF) {
    const int lane = threadIdx.x & 63;
    const int wave = threadIdx.x >> 6;   // 0..3
    const int m = lane & 15, q = lane >> 4;
    const int i0 = blockIdx.x * 64;
    const int jbase = blockIdx.y * 512;

    __shared__ __align__(16) unsigned short Slds[2][64][72];  // 18.4 KB

    u32x4 afr[4][2];
    float si[4][4];
#pragma unroll
    for (int mt = 0; mt < 4; ++mt) {
#pragma unroll
        for (int ks = 0; ks < 2; ++ks)
            afr[mt][ks] = *(const u32x4*)(tbf + (i0 + mt * 16 + m) * BD + ks * 32 + q * 8);
#pragma unroll
        for (int r = 0; r < 4; ++r) si[mt][r] = s[i0 + mt * 16 + q * 4 + r];
    }
    float dsum[4][4] = {};

    // prefetch iter-0 B operand
    int jw = jbase + wave * 16;
    u32x4 b0 = *(const u32x4*)(tbf + (jw + m) * BD + q * 8);
    u32x4 b1 = *(const u32x4*)(tbf + (jw + m) * BD + 32 + q * 8);
    float sj = s[jw + m];

    for (int it8 = 0; it8 < 8; ++it8) {
        const int J = jbase + it8 * 64;
        const int p = it8 & 1;
        f32x4 c[4];
#pragma unroll
        for (int mt = 0; mt < 4; ++mt) {
            c[mt] = f32x4{0.f, 0.f, 0.f, 0.f};
            c[mt] = mfma16(afr[mt][0], b0, c[mt]);
            c[mt] = mfma16(afr[mt][1], b1, c[mt]);
        }
        // prefetch next iter's B while transform runs
        int jn = (it8 < 7) ? J + 64 + wave * 16 : jbase + wave * 16;
        u32x4 nb0 = *(const u32x4*)(tbf + (jn + m) * BD + q * 8);
        u32x4 nb1 = *(const u32x4*)(tbf + (jn + m) * BD + 32 + q * 8);
        float nsj = s[jn + m];
#pragma unroll
        for (int mt = 0; mt < 4; ++mt)
#pragma unroll
            for (int r = 0; r < 4; ++r) {
                float a = adj_fn(c[mt][r], si[mt][r] + sj);
                dsum[mt][r] += a;
                Slds[p][mt * 16 + q * 4 + r][wave * 16 + m] = f2bf(a);
            }
        __syncthreads();
        // frag store: wave w -> it-tile (i0/16 + w), k-tiles J/32 + {0,1}
#pragma unroll
        for (int ktl = 0; ktl < 2; ++ktl) {
            u32x4 v = *(const u32x4*)(&Slds[p][wave * 16 + m][ktl * 32 + q * 8]);
            *(u32x4*)(adjF + ((size_t)((i0 >> 4) + wave) * 256 + (J >> 5) + ktl) * 512 + lane * 8) = v;
        }
        b0 = nb0; b1 = nb1; sj = nsj;
    }

#pragma unroll
    for (int mt = 0; mt < 4; ++mt)
#pragma unroll
        for (int r = 0; r < 4; ++r) {
            float v = dsum[mt][r];
            v += __shfl_xor(v, 1); v += __shfl_xor(v, 2);
            v += __shfl_xor(v, 4); v += __shfl_xor(v, 8);
            if (m == 0) atomicAdd(&d[i0 + mt * 16 + q * 4 + r], v);
        }
}

// ---------------- dinv ----------------
__global__ void dinv_kernel(const float* __restrict__ d, float* __restrict__ dinv) {
    int i = blockIdx.x * 256 + threadIdx.x;
    dinv[i] = rsqrtf(d[i] + 1e-8f);
}

// ---------------- fc: fcF = frag-major bf16(dinv[i]*(cbnF @ WF + b)) ----------------
__global__ __launch_bounds__(256) void fc_kernel(const unsigned short* __restrict__ cbnF,
                                                 const unsigned short* __restrict__ WF,
                                                 const float* __restrict__ bias,
                                                 const float* __restrict__ dinv,
                                                 unsigned short* __restrict__ fcF) {
    const int lane = threadIdx.x & 63;
    const int wave = threadIdx.x >> 6;
    const int m = lane & 15, q = lane >> 4;
    const int i0 = blockIdx.x * 64;
    const int ntg = blockIdx.y * 4 + wave;   // 0..31

    const u32x4* Ag = (const u32x4*)cbnF;
    const u32x4* Bg = (const u32x4*)WF;

    f32x4 acc[4] = {};
#pragma unroll
    for (int ct = 0; ct < 16; ++ct) {
        u32x4 bfr = Bg[((size_t)ntg * 16 + ct) * 64 + lane];
#pragma unroll
        for (int mt = 0; mt < 4; ++mt) {
            u32x4 afr = Ag[(((size_t)(i0 >> 4) + mt) * 16 + ct) * 64 + lane];
            acc[mt] = mfma16(afr, bfr, acc[mt]);
        }
    }
    float bv = bias[ntg * 16 + m];
#pragma unroll
    for (int mt = 0; mt < 4; ++mt) {
        int i = i0 + mt * 16 + q * 4;   // conv2 k-index (fc row)
        ushort4 o;
        o.x = f2bf((acc[mt][0] + bv) * dinv[i + 0]);
        o.y = f2bf((acc[mt][1] + bv) * dinv[i + 1]);
        o.z = f2bf((acc[mt][2] + bv) * dinv[i + 2]);
        o.w = f2bf((acc[mt][3] + bv) * dinv[i + 3]);
        size_t off = ((size_t)ntg * 256 + (i >> 5)) * 512
                   + (size_t)((i >> 3) & 3) * 128 + m * 8 + (q & 1) * 4;
        *(ushort4*)(fcF + off) = o;
    }
}

// ---------------- conv2: out = sigmoid(dvi * (adj @ fc2)) — frag-major GEMM ----------------
// M=8192 N=512 K=8192. Block 128x128, 512 thr / 8 waves = (kg,rg,cg) 2x2x2;
// wave tile 64x64 (4x4 16^2 frags), kg halves take alternating kt, LDS f32 reduce at end.
// COUNTED-VMCNT RING, TEMPLATE-SHAPED PHASE (fix of round-4 regression): round 4 put
// ds_reads AFTER the barrier behind sched_barrier(0) fences -> 8 ds_read_b128 sat
// serially on the critical path each phase (29% MfmaUtil). Template shape (m201, 62%):
//   glds(chunk h+3) ; ds_read(chunk h) ; s_waitcnt vmcnt(8) ; setprio MFMA x16 ; s_barrier
// with NO sched_barrier inside: compiler interleaves ds_reads with MFMAs via
// fine-grained lgkmcnt; read latency hides under the vmcnt wait + barrier skew;
// vmcnt NEVER drains to 0 in the main loop (8 DMAs always in flight).
// Ring: chunk = K=64 (32 frags, 32 KB), 4 slots (128 KB), depth-3 prefetch.
// Race safety: glds(h+3) targets slot (h+3)&3 = chunk h-1's slot; chunk h-1's reads
// were lgkm-complete before phase h-1's end barrier, which precedes any phase-h glds.
// Chunk h+1 completeness for phase h+1: each wave waits ITS vmcnt(8) pre-barrier;
// barrier joins all waves' DMA contributions. No other vmem in the loop.
// Swizzle: xcd=bid&7; 4 cblk blocks of an iblk co-resident on ONE xcd => A slice
// fetched from HBM once, L2 serves re-reads.
__global__ __launch_bounds__(512, 2) void conv2_kernel(const unsigned short* __restrict__ adjF,
                                                       const unsigned short* __restrict__ fcF,
                                                       const float* __restrict__ dinv,
                                                       float* __restrict__ out) {
    const int bid = blockIdx.x;
    const int xcd = bid & 7;
    const int g = bid >> 3;               // 0..31
    const int iblk = (g >> 2) * 8 + xcd;  // 0..63
    const int cblk = g & 3;
    const int i0 = iblk * 128;

    const int lane = threadIdx.x & 63;
    const int wave = threadIdx.x >> 6;    // 0..7
    const int kg = wave >> 2;             // kt parity: kg0 -> even kt, kg1 -> odd kt
    const int rg = (wave >> 1) & 1;       // row half (64 rows)
    const int cg = wave & 1;              // col half (64 cols)
    const int m = lane & 15, q = lane >> 4;

    // 4-slot ring of K=64 chunks: [ring][slot][frag]; slot 0-15 = A(ktl*8+it),
    // 16-31 = B(ktl*8+nt). 128 KB.
    __shared__ __align__(16) unsigned short S[4][32][512];

    // staging: fid = wave*4+j in [0,32): isB=fid>>4, ktl=(fid>>3)&1, sl=fid&7
    const unsigned short* src[4];
    int slot[4];
#pragma unroll
    for (int j = 0; j < 4; ++j) {
        int fid = wave * 4 + j;
        int isB = fid >> 4;
        int ktl = (fid >> 3) & 1;
        int sl = fid & 7;
        slot[j] = isB * 16 + ktl * 8 + sl;
        src[j] = isB
            ? fcF  + ((size_t)(cblk * 8 + sl) * 256 + ktl) * 512 + lane * 8
            : adjF + ((size_t)((i0 >> 4) + sl) * 256 + ktl) * 512 + lane * 8;
        // chunk h covers kt = 2h+ktl -> advance 1024 ushorts (2 KB) per chunk
    }

    f32x4 acc[4][4] = {};

    // prologue: issue chunks 0..2 (12 outstanding glds16 per wave), land chunk 0
#pragma unroll
    for (int h = 0; h < 3; ++h)
#pragma unroll
        for (int j = 0; j < 4; ++j)
            glds16(src[j] + (size_t)h * 1024, &S[h][slot[j]][0]);
    asm volatile("s_waitcnt vmcnt(8)" ::: "memory");
    __builtin_amdgcn_s_barrier();

    const int arow = kg * 8 + rg * 4;        // this wave's A slot base
    const int brow = 16 + kg * 8 + cg * 4;   // this wave's B slot base

#define CONV2_PHASE(HH, WAITN)                                                  \
    {                                                                           \
        if ((HH) <= 124) {                                                      \
            const int hn_ = (HH) + 3;                                           \
            _Pragma("unroll")                                                   \
            for (int j = 0; j < 4; ++j)                                         \
                glds16(src[j] + (size_t)hn_ * 1024, &S[hn_ & 3][slot[j]][0]);   \
        }                                                                       \
        u32x4 pa_[4], pb_[4];                                                   \
        _Pragma("unroll")                                                       \
        for (int t = 0; t < 4; ++t) {                                           \
            pa_[t] = *(const u32x4*)&S[(HH) & 3][arow + t][lane * 8];           \
            pb_[t] = *(const u32x4*)&S[(HH) & 3][brow + t][lane * 8];           \
        }                                                                       \
        asm volatile("s_waitcnt vmcnt(" #WAITN ")" ::: "memory");               \
        __builtin_amdgcn_s_setprio(1);                                          \
        _Pragma("unroll")                                                       \
        for (int mt = 0; mt < 4; ++mt)                                          \
            _Pragma("unroll")                                                   \
            for (int ct = 0; ct < 4; ++ct)                                      \
                acc[mt][ct] = mfma16(pa_[mt], pb_[ct], acc[mt][ct]);            \
        __builtin_amdgcn_s_setprio(0);                                          \
        __builtin_amdgcn_s_barrier();                                           \
    }

    for (int h = 0; h < 125; ++h) CONV2_PHASE(h, 8);
    CONV2_PHASE(125, 4);
    CONV2_PHASE(126, 0);
    CONV2_PHASE(127, 0);
#undef CONV2_PHASE

    // cross-kg combine: kg1 publishes acc (f32, stride 132 to dodge bank conflicts),
    // kg0 adds + epilogue. Reuses S: red spans 67.6 KB (ring slots 0-2); the last
    // in-loop LDS reads of that region were chunk 126 (slot 2), fenced two barriers
    // before any epilogue write. Phase-127 reads used slot 3 (disjoint).
    float* red = (float*)&S[0][0][0];   // 128*132*4 = 67.6 KB < 128 KB
    if (kg == 1) {
#pragma unroll
        for (int mt = 0; mt < 4; ++mt)
#pragma unroll
            for (int ct = 0; ct < 4; ++ct)
#pragma unroll
                for (int r = 0; r < 4; ++r)
                    red[(rg * 64 + mt * 16 + q * 4 + r) * 132 + cg * 64 + ct * 16 + m] = acc[mt][ct][r];
    }
    __syncthreads();
    if (kg == 0) {
#pragma unroll
        for (int mt = 0; mt < 4; ++mt)
#pragma unroll
            for (int ct = 0; ct < 4; ++ct)
#pragma unroll
                for (int r = 0; r < 4; ++r) {
                    int lrow = rg * 64 + mt * 16 + q * 4 + r;
                    int row = i0 + lrow;
                    int lcol = cg * 64 + ct * 16 + m;
                    float v = acc[mt][ct][r] + red[lrow * 132 + lcol];
                    float xv = v * dinv[row];
                    out[(size_t)row * CDIM + cblk * 128 + lcol] = 1.0f / (1.0f + __expf(-xv));
                }
    }
}

extern "C" void kernel_launch(void* const* d_in, const int* in_sizes, int n_in,
                              void* d_out, int out_size, void* d_ws, size_t ws_size,
                              hipStream_t stream) {
    const float* bbn = (const float*)d_in[0];
    const float* cbn = (const float*)d_in[1];
    const float* W   = (const float*)d_in[2];
    const float* b   = (const float*)d_in[3];
    float* out = (float*)d_out;  // reference output is float32

    char* ws = (char*)d_ws;
    unsigned short* tbf  = (unsigned short*)(ws);                 // 1 MB
    float* s             = (float*)(ws + (1u << 20));             // 32 KB
    float* d             = (float*)(ws + (1u << 20) + 32768);     // 32 KB
    float* dinv          = (float*)(ws + (1u << 20) + 65536);     // 32 KB
    unsigned short* fcF  = (unsigned short*)(ws + (2u << 20));    // 8 MB
    unsigned short* cbnF = (unsigned short*)(ws + (10u << 20));   // 8 MB
    unsigned short* WF   = (unsigned short*)(ws + (18u << 20));   // 0.5 MB
    unsigned short* adjF = (unsigned short*)(ws + (19u << 20));   // 128 MiB

    prep_kernel<<<NN * 16 / 256, 256, 0, stream>>>(bbn, tbf, s);
    prep_cbn_kernel<<<512, 256, 0, stream>>>(cbn, cbnF);
    prep_w_kernel<<<128, 256, 0, stream>>>(W, WF);
    hipMemsetAsync(d, 0, NN * sizeof(float), stream);
    scoredeg_kernel<<<dim3(NN / 64, 16), 256, 0, stream>>>(tbf, s, d, adjF);
    dinv_kernel<<<NN / 256, 256, 0, stream>>>(d, dinv);
    fc_kernel<<<dim3(NN / 64, 8), 256, 0, stream>>>(cbnF, WF, b, dinv, fcF);
    conv2_kernel<<<256, 512, 0, stream>>>(adjF, fcF, dinv, out);
}

// Round 7
// 203.964 us; speedup vs baseline: 1.0300x; 1.0112x over previous
//
#include <hip/hip_runtime.h>
#include <hip/hip_bf16.h>

// N=8192 rows, BD=64 code dim, CD=512 channel dim
#define NN 8192
#define BD 64
#define CDIM 512

typedef __attribute__((ext_vector_type(4))) float f32x4;
typedef __attribute__((ext_vector_type(4))) unsigned int u32x4;
typedef __attribute__((ext_vector_type(8))) __bf16 bf16x8;

// Fragment-major layouts (elems = unsigned short), frag = 512 ushorts = 1 KB:
//  adjF frag(it,kt): it=i/16 [0,512), kt=k/32 [0,256): off=(it*256+kt)*512+lane*8
//    lane=q*16+m holds adj[it*16+m][kt*32+q*8 .. +7]   (A-operand layout)
//  fcF  frag(nt,kt): nt=n/16 [0,32), kt=k/32 [0,256):  off=(nt*256+kt)*512+lane*8
//    lane holds fc2[kt*32+q*8 .. +7][nt*16+m]          (B-operand layout)
//  cbnF frag(it,ct): off=(it*16+ct)*512+lane*8  (A) ;  WF frag(nt,ct): off=(nt*16+ct)*512+lane*8 (B)
//
// conv2 staging-wall note (R0-R5 ablation): five schedule variants (2-barrier,
// C=4 kg-split, all-LDS early-issue, counted-vmcnt x2) all land at ~23 B/cyc/CU
// of VMEM staging traffic = the same rate as m97/m201/HipKittens/hipBLASLt on
// this chip. conv2 at 128x128 full-K is staging-bandwidth-bound at ~74 us;
// schedule changes are neutral. Remaining levers live OUTSIDE conv2.

static __device__ __forceinline__ unsigned short f2bf(float x) {
    unsigned int u = __float_as_uint(x);
    u += 0x7fffu + ((u >> 16) & 1u);   // RTNE
    return (unsigned short)(u >> 16);
}

static __device__ __forceinline__ f32x4 mfma16(u32x4 a, u32x4 b, f32x4 c) {
    return __builtin_amdgcn_mfma_f32_16x16x32_bf16(
        __builtin_bit_cast(bf16x8, a), __builtin_bit_cast(bf16x8, b), c, 0, 0, 0);
}

static __device__ __forceinline__ u32x4 cvt8(const float* __restrict__ p) {
    float4 a = *(const float4*)p;
    float4 b = *(const float4*)(p + 4);
    u32x4 r;
    r.x = (unsigned)f2bf(a.x) | ((unsigned)f2bf(a.y) << 16);
    r.y = (unsigned)f2bf(a.z) | ((unsigned)f2bf(a.w) << 16);
    r.z = (unsigned)f2bf(b.x) | ((unsigned)f2bf(b.y) << 16);
    r.w = (unsigned)f2bf(b.z) | ((unsigned)f2bf(b.w) << 16);
    return r;
}

// adj = (max(1 - |2*dot - si - sj|/64, 0))^1.4
static __device__ __forceinline__ float adj_fn(float dot, float sij) {
    float x = fabsf(fmaf(2.0f, dot, -sij));
    float base = fmaxf(fmaf(-0.015625f, x, 1.0f), 0.0f);
    return exp2f(1.4f * __log2f(base));   // pow(0,1.4)=0 via -inf
}

// ---------------- fused prep: 4 independent jobs in one dispatch ----------------
// blocks [0,512):    bbn -> bf16 row-major tbf, row sums s
// blocks [512,1024): cbn -> A-frag-major cbnF
// blocks [1024,1152): W -> B-frag-major WF
// blocks [1152,1184): d[i] = 0  (replaces hipMemsetAsync; ordering vs scoredeg's
//                     atomics is guaranteed by the kernel boundary)
__global__ __launch_bounds__(256) void fused_prep_kernel(const float* __restrict__ bbn,
                                                         const float* __restrict__ cbn,
                                                         const float* __restrict__ W,
                                                         unsigned short* __restrict__ tbf,
                                                         float* __restrict__ s,
                                                         unsigned short* __restrict__ cbnF,
                                                         unsigned short* __restrict__ WF,
                                                         float* __restrict__ d) {
    const int blk = blockIdx.x;
    const int lane = threadIdx.x & 63;
    const int wave = threadIdx.x >> 6;
    const int m = lane & 15, q = lane >> 4;

    if (blk < 512) {
        // prep: 16 threads/row
        int gid = blk * 256 + threadIdx.x;
        int row = gid >> 4;
        int part = gid & 15;
        float4 v = *(const float4*)(bbn + row * BD + part * 4);
        ushort4 o;
        o.x = f2bf(v.x); o.y = f2bf(v.y); o.z = f2bf(v.z); o.w = f2bf(v.w);
        *(ushort4*)(tbf + row * BD + part * 4) = o;
        float ps = v.x + v.y + v.z + v.w;
        ps += __shfl_xor(ps, 1); ps += __shfl_xor(ps, 2);
        ps += __shfl_xor(ps, 4); ps += __shfl_xor(ps, 8);
        if (part == 0) s[row] = ps;
    } else if (blk < 1024) {
        // prep_cbn
        int b = blk - 512;
#pragma unroll
        for (int t = 0; t < 4; ++t) {
            int f = b * 16 + wave * 4 + t;   // 8192 frags
            int it = f >> 4, ct = f & 15;
            u32x4 v = cvt8(cbn + (size_t)(it * 16 + m) * CDIM + ct * 32 + q * 8);
            *(u32x4*)(cbnF + (size_t)f * 512 + lane * 8) = v;
        }
    } else if (blk < 1152) {
        // prep_w
        int b = blk - 1024;
        int f = b * 4 + wave;   // 512 frags
        int nt = f >> 4, ct = f & 15;
        u32x4 v = cvt8(W + (size_t)(nt * 16 + m) * CDIM + ct * 32 + q * 8);
        *(u32x4*)(WF + (size_t)f * 512 + lane * 8) = v;
    } else {
        // zero d
        int i = (blk - 1152) * 256 + threadIdx.x;
        d[i] = 0.0f;
    }
}

// ---------------- scoredeg: adjF = frag-major bf16 adj, d[i] = row sums ----------------
// grid (128 i-tiles, 16 j-chunks of 512) = 2048 blocks -> 8 blocks/CU.
// Double-buffered LDS: ONE barrier per 64-j tile (write p | barrier | read p || write p^1 ...).
__global__ __launch_bounds__(256) void scoredeg_kernel(const unsigned short* __restrict__ tbf,
                                                       const float* __restrict__ s,
                                                       float* __restrict__ d,
                                                       unsigned short* __restrict__ adjF) {
    const int lane = threadIdx.x & 63;
    const int wave = threadIdx.x >> 6;   // 0..3
    const int m = lane & 15, q = lane >> 4;
    const int i0 = blockIdx.x * 64;
    const int jbase = blockIdx.y * 512;

    __shared__ __align__(16) unsigned short Slds[2][64][72];  // 18.4 KB

    u32x4 afr[4][2];
    float si[4][4];
#pragma unroll
    for (int mt = 0; mt < 4; ++mt) {
#pragma unroll
        for (int ks = 0; ks < 2; ++ks)
            afr[mt][ks] = *(const u32x4*)(tbf + (i0 + mt * 16 + m) * BD + ks * 32 + q * 8);
#pragma unroll
        for (int r = 0; r < 4; ++r) si[mt][r] = s[i0 + mt * 16 + q * 4 + r];
    }
    float dsum[4][4] = {};

    // prefetch iter-0 B operand
    int jw = jbase + wave * 16;
    u32x4 b0 = *(const u32x4*)(tbf + (jw + m) * BD + q * 8);
    u32x4 b1 = *(const u32x4*)(tbf + (jw + m) * BD + 32 + q * 8);
    float sj = s[jw + m];

    for (int it8 = 0; it8 < 8; ++it8) {
        const int J = jbase + it8 * 64;
        const int p = it8 & 1;
        f32x4 c[4];
#pragma unroll
        for (int mt = 0; mt < 4; ++mt) {
            c[mt] = f32x4{0.f, 0.f, 0.f, 0.f};
            c[mt] = mfma16(afr[mt][0], b0, c[mt]);
            c[mt] = mfma16(afr[mt][1], b1, c[mt]);
        }
        // prefetch next iter's B while transform runs
        int jn = (it8 < 7) ? J + 64 + wave * 16 : jbase + wave * 16;
        u32x4 nb0 = *(const u32x4*)(tbf + (jn + m) * BD + q * 8);
        u32x4 nb1 = *(const u32x4*)(tbf + (jn + m) * BD + 32 + q * 8);
        float nsj = s[jn + m];
#pragma unroll
        for (int mt = 0; mt < 4; ++mt)
#pragma unroll
            for (int r = 0; r < 4; ++r) {
                float a = adj_fn(c[mt][r], si[mt][r] + sj);
                dsum[mt][r] += a;
                Slds[p][mt * 16 + q * 4 + r][wave * 16 + m] = f2bf(a);
            }
        __syncthreads();
        // frag store: wave w -> it-tile (i0/16 + w), k-tiles J/32 + {0,1}
#pragma unroll
        for (int ktl = 0; ktl < 2; ++ktl) {
            u32x4 v = *(const u32x4*)(&Slds[p][wave * 16 + m][ktl * 32 + q * 8]);
            *(u32x4*)(adjF + ((size_t)((i0 >> 4) + wave) * 256 + (J >> 5) + ktl) * 512 + lane * 8) = v;
        }
        b0 = nb0; b1 = nb1; sj = nsj;
    }

#pragma unroll
    for (int mt = 0; mt < 4; ++mt)
#pragma unroll
        for (int r = 0; r < 4; ++r) {
            float v = dsum[mt][r];
            v += __shfl_xor(v, 1); v += __shfl_xor(v, 2);
            v += __shfl_xor(v, 4); v += __shfl_xor(v, 8);
            if (m == 0) atomicAdd(&d[i0 + mt * 16 + q * 4 + r], v);
        }
}

// ---------------- fc: fcF = frag-major bf16(rsqrt(d[i])*(cbnF @ WF + b)) ----------------
// dinv computed inline from d (dinv_kernel dispatch eliminated).
__global__ __launch_bounds__(256) void fc_kernel(const unsigned short* __restrict__ cbnF,
                                                 const unsigned short* __restrict__ WF,
                                                 const float* __restrict__ bias,
                                                 const float* __restrict__ d,
                                                 unsigned short* __restrict__ fcF) {
    const int lane = threadIdx.x & 63;
    const int wave = threadIdx.x >> 6;
    const int m = lane & 15, q = lane >> 4;
    const int i0 = blockIdx.x * 64;
    const int ntg = blockIdx.y * 4 + wave;   // 0..31

    const u32x4* Ag = (const u32x4*)cbnF;
    const u32x4* Bg = (const u32x4*)WF;

    f32x4 acc[4] = {};
#pragma unroll
    for (int ct = 0; ct < 16; ++ct) {
        u32x4 bfr = Bg[((size_t)ntg * 16 + ct) * 64 + lane];
#pragma unroll
        for (int mt = 0; mt < 4; ++mt) {
            u32x4 afr = Ag[(((size_t)(i0 >> 4) + mt) * 16 + ct) * 64 + lane];
            acc[mt] = mfma16(afr, bfr, acc[mt]);
        }
    }
    float bv = bias[ntg * 16 + m];
#pragma unroll
    for (int mt = 0; mt < 4; ++mt) {
        int i = i0 + mt * 16 + q * 4;   // conv2 k-index (fc row)
        ushort4 o;
        o.x = f2bf((acc[mt][0] + bv) * rsqrtf(d[i + 0] + 1e-8f));
        o.y = f2bf((acc[mt][1] + bv) * rsqrtf(d[i + 1] + 1e-8f));
        o.z = f2bf((acc[mt][2] + bv) * rsqrtf(d[i + 2] + 1e-8f));
        o.w = f2bf((acc[mt][3] + bv) * rsqrtf(d[i + 3] + 1e-8f));
        size_t off = ((size_t)ntg * 256 + (i >> 5)) * 512
                   + (size_t)((i >> 3) & 3) * 128 + m * 8 + (q & 1) * 4;
        *(ushort4*)(fcF + off) = o;
    }
}

// ---------------- conv2: out = sigmoid(dvi * (adj @ fc2)) — frag-major GEMM ----------------
// M=8192 N=512 K=8192. Block 128 rows x 128 cols, 512 thr / 8 waves; wave = 16-col slice
// spanning all 128 rows (acc 8 frags). K-chunk 128 in dbuf LDS (64 KB), 1 barrier/chunk.
// B prefetched 4 kt deep (620 cyc MFMA cover >= L3 latency).
// Swizzle: 256 blocks, xcd=bid&7; iblk=(g>>2)*8+xcd -> the 4 cblk blocks of an iblk are
// co-resident on ONE xcd => A slice fetched from HBM once, L2 serves re-reads.
// (Best-measured schedule of the R0-R5 ablation: 74.0-74.2 us, staging-wall bound.)
__global__ __launch_bounds__(512) void conv2_kernel(const unsigned short* __restrict__ adjF,
                                                    const unsigned short* __restrict__ fcF,
                                                    const float* __restrict__ dd,
                                                    float* __restrict__ out) {
    const int bid = blockIdx.x;
    const int xcd = bid & 7;
    const int g = bid >> 3;               // 0..31
    const int iblk = (g >> 2) * 8 + xcd;  // 0..63
    const int cblk = g & 3;
    const int i0 = iblk * 128;

    const int lane = threadIdx.x & 63;
    const int wave = threadIdx.x >> 6;    // 0..7
    const int m = lane & 15, q = lane >> 4;
    const int nt = cblk * 8 + wave;       // 0..31: this wave's 16 output cols

    __shared__ __align__(16) unsigned short Abuf[2][4][8][512];  // 64 KB [buf][ktl][it][frag]

    const u32x4* Ag = (const u32x4*)adjF;
    const u32x4* Bg = (const u32x4*)fcF;
    const int itw = (i0 >> 4) + wave;     // wave stages it-tile = wave

    f32x4 acc[8] = {};
    u32x4 st[4], bq[4];

    // prologue: stage chunk 0, preload B kt 0..3
#pragma unroll
    for (int ktl = 0; ktl < 4; ++ktl)
        st[ktl] = Ag[((size_t)itw * 256 + ktl) * 64 + lane];
#pragma unroll
    for (int ktl = 0; ktl < 4; ++ktl)
        *(u32x4*)&Abuf[0][ktl][wave][lane * 8] = st[ktl];
#pragma unroll
    for (int ktl = 0; ktl < 4; ++ktl)
        bq[ktl] = Bg[((size_t)nt * 256 + ktl) * 64 + lane];
    __syncthreads();

    for (int c = 0; c < 64; ++c) {
        const int kb = c * 4;
        const int cur = c & 1, nxt = cur ^ 1;
        const int kbn = (c < 63) ? kb + 4 : kb;
        // A: prefetch next chunk into regs (whole MFMA phase covers HBM latency)
#pragma unroll
        for (int ktl = 0; ktl < 4; ++ktl)
            st[ktl] = Ag[((size_t)itw * 256 + kbn + ktl) * 64 + lane];
#pragma unroll
        for (int ktl = 0; ktl < 4; ++ktl) {
            int ktn = kb + ktl + 4; if (ktn > 255) ktn = 255;
            u32x4 bn = Bg[((size_t)nt * 256 + ktn) * 64 + lane];
            u32x4 pa[8];
#pragma unroll
            for (int mt = 0; mt < 8; ++mt)
                pa[mt] = *(const u32x4*)&Abuf[cur][ktl][mt][lane * 8];
#pragma unroll
            for (int mt = 0; mt < 8; ++mt)
                acc[mt] = mfma16(pa[mt], bq[ktl], acc[mt]);
            bq[ktl] = bn;
        }
        // publish next chunk (safe: buf[nxt] last read in c-1, barrier since)
#pragma unroll
        for (int ktl = 0; ktl < 4; ++ktl)
            *(u32x4*)&Abuf[nxt][ktl][wave][lane * 8] = st[ktl];
        __syncthreads();
    }

#pragma unroll
    for (int mt = 0; mt < 8; ++mt)
#pragma unroll
        for (int r = 0; r < 4; ++r) {
            int row = i0 + mt * 16 + q * 4 + r;
            float dv = rsqrtf(dd[row] + 1e-8f);
            float xv = acc[mt][r] * dv;
            out[(size_t)row * CDIM + cblk * 128 + wave * 16 + m] = 1.0f / (1.0f + __expf(-xv));
        }
}

extern "C" void kernel_launch(void* const* d_in, const int* in_sizes, int n_in,
                              void* d_out, int out_size, void* d_ws, size_t ws_size,
                              hipStream_t stream) {
    const float* bbn = (const float*)d_in[0];
    const float* cbn = (const float*)d_in[1];
    const float* W   = (const float*)d_in[2];
    const float* b   = (const float*)d_in[3];
    float* out = (float*)d_out;  // reference output is float32

    char* ws = (char*)d_ws;
    unsigned short* tbf  = (unsigned short*)(ws);                 // 1 MB
    float* s             = (float*)(ws + (1u << 20));             // 32 KB
    float* d             = (float*)(ws + (1u << 20) + 32768);     // 32 KB
    unsigned short* fcF  = (unsigned short*)(ws + (2u << 20));    // 8 MB
    unsigned short* cbnF = (unsigned short*)(ws + (10u << 20));   // 8 MB
    unsigned short* WF   = (unsigned short*)(ws + (18u << 20));   // 0.5 MB
    unsigned short* adjF = (unsigned short*)(ws + (19u << 20));   // 128 MiB

    // 4 dispatches (was 9): fused preps+zero -> scoredeg -> fc -> conv2
    fused_prep_kernel<<<1184, 256, 0, stream>>>(bbn, cbn, W, tbf, s, cbnF, WF, d);
    scoredeg_kernel<<<dim3(NN / 64, 16), 256, 0, stream>>>(tbf, s, d, adjF);
    fc_kernel<<<dim3(NN / 64, 8), 256, 0, stream>>>(cbnF, WF, b, d, fcF);
    conv2_kernel<<<256, 512, 0, stream>>>(adjF, fcF, d, out);
}